// Round 12
// baseline (86.985 us; speedup 1.0000x reference)
//
#include <hip/hip_runtime.h>
#include <math.h>

#define EPSF    1e-8f
#define SLOPEF  0.2f
#define GS_EPSF 1e-6f

#define NB   4
#define KZ   4
#define BKT  16     // NB*KZ
#define NPT  2048
#define DIM  32

#define COMP(v,kk) ((kk)==0?(v).x:(kk)==1?(v).y:(kk)==2?(v).z:(v).w)

typedef float f2 __attribute__((ext_vector_type(2)));

__device__ __forceinline__ void fma4(float4& acc, float s, const float4& v) {
  acc.x = fmaf(s, v.x, acc.x); acc.y = fmaf(s, v.y, acc.y);
  acc.z = fmaf(s, v.z, acc.z); acc.w = fmaf(s, v.w, acc.w);
}

// ---------------------------------------------------------------------------
// Kernel 0 (round-9 exact): pts AoS + ptsP pair-packed + wpk weight pack.
// ---------------------------------------------------------------------------
__global__ __launch_bounds__(256) void prep_coords(
    const float* __restrict__ node, const float* __restrict__ z,
    const float* __restrict__ Wp1, const float* __restrict__ Wp3,
    float4* __restrict__ pts, float* __restrict__ ptsPf,
    float4* __restrict__ wpk) {
  if (blockIdx.x == 0) {
    int i = threadIdx.x;                   // 256 entries each
    int og = i & 7, c = i >> 3;
    wpk[i]       = make_float4(Wp1[og * 32 + c], Wp1[(og + 8) * 32 + c],
                               Wp1[(og + 16) * 32 + c], Wp1[(og + 24) * 32 + c]);
    wpk[256 + i] = make_float4(Wp3[og * 32 + c], Wp3[(og + 8) * 32 + c],
                               Wp3[(og + 16) * 32 + c], Wp3[(og + 24) * 32 + c]);
  }
  int t = blockIdx.x * 256 + threadIdx.x;
  if (t >= BKT * NPT) return;
  int bk = t >> 11, n = t & (NPT - 1);
  int b = bk >> 2, kz = bk & 3;
  const float2* np2 = (const float2*)(node + (size_t)(b * NPT + n) * 6);
  const float2* zp2 = (const float2*)(z + (size_t)((b * KZ + kz) * NPT + n) * 6);
  float ch[6];
#pragma unroll
  for (int j = 0; j < 3; ++j) {
    float2 a = np2[j], c = zp2[j];
    ch[j]     = a.x + c.x;
    ch[3 + j] = a.y + c.y;
  }
  float xx = 0.f;
#pragma unroll
  for (int h = 0; h < 6; ++h) xx = fmaf(ch[h], ch[h], xx);
  pts[(size_t)t * 2 + 0] = make_float4(ch[0], ch[1], ch[2], ch[3]);
  pts[(size_t)t * 2 + 1] = make_float4(ch[4], ch[5], xx, 0.f);
  size_t pbase = (size_t)(t >> 1) * 16 + (t & 1);
#pragma unroll
  for (int c = 0; c < 6; ++c) ptsPf[pbase + c * 2] = ch[c];
  ptsPf[pbase + 12] = xx;
}

// ---------------------------------------------------------------------------
__device__ __forceinline__ void ins3m(float s, int j,
    float& v0, float& v1, float& v2, int& i0, int& i1, int& i2) {
  bool c0 = s > v0, c1 = s > v1, c2 = s > v2;
  float nv0 = fmaxf(v0, s);
  float nv1 = __builtin_amdgcn_fmed3f(v0, v1, s);
  float nv2 = __builtin_amdgcn_fmed3f(v1, v2, s);
  i2 = c1 ? i1 : (c2 ? j : i2);
  i1 = c0 ? i0 : (c1 ? j : i1);
  i0 = c0 ? j : i0;
  v0 = nv0; v1 = nv1; v2 = nv2;
}

__device__ __forceinline__ void ce(float& vx, int& ix, float& vy, int& iy) {
  float av = vx, bv = vy; int ai = ix, bi = iy;
  bool sw = (bv > av) || (bv == av && bi < ai);
  vx = sw ? bv : av; vy = sw ? av : bv;
  ix = sw ? bi : ai; iy = sw ? ai : bi;
}

// ---------------------------------------------------------------------------
// 128-point scan serving TWO queries per lane (q0, q1). 4 loads per pair are
// amortized over both queries — per-score load cost halves vs round 9.
// Score chain order bit-identical to rounds 8-11.
// ---------------------------------------------------------------------------
template <bool SELF>
__device__ __forceinline__ void scan128Q2(const float4* __restrict__ pp4,
    int j0, int q0, int q1,
    const float4 qa0, const float4 qb0, const float4 qa1, const float4 qb1,
    float& a0, float& a1, float& a2, int& ia0, int& ia1, int& ia2,
    float& b0, float& b1, float& b2, int& ib0, int& ib1, int& ib2) {
  f2 q0x = {qa0.x, qa0.x}, q0y = {qa0.y, qa0.y}, q0z = {qa0.z, qa0.z}, q0w = {qa0.w, qa0.w};
  f2 q0u = {qb0.x, qb0.x}, q0v = {qb0.y, qb0.y};
  f2 q1x = {qa1.x, qa1.x}, q1y = {qa1.y, qa1.y}, q1z = {qa1.z, qa1.z}, q1w = {qa1.w, qa1.w};
  f2 q1u = {qb1.x, qb1.x}, q1v = {qb1.y, qb1.y};
  f2 mh = {-0.5f, -0.5f};
#pragma unroll 2
  for (int pr = 0; pr < 64; ++pr) {
    float4 L0 = pp4[pr * 4 + 0], L1 = pp4[pr * 4 + 1];
    float4 L2 = pp4[pr * 4 + 2], L3 = pp4[pr * 4 + 3];
    f2 ax = {L0.x, L0.y}, ay = {L0.z, L0.w};
    f2 az = {L1.x, L1.y}, aw = {L1.z, L1.w};
    f2 au = {L2.x, L2.y}, av = {L2.z, L2.w};
    f2 Xa = {L3.x, L3.y};
    f2 s0 = q0x * ax;
    s0 = __builtin_elementwise_fma(q0y, ay, s0);
    s0 = __builtin_elementwise_fma(q0z, az, s0);
    s0 = __builtin_elementwise_fma(q0w, aw, s0);
    s0 = __builtin_elementwise_fma(q0u, au, s0);
    s0 = __builtin_elementwise_fma(q0v, av, s0);
    s0 = __builtin_elementwise_fma(mh, Xa, s0);
    f2 s1 = q1x * ax;
    s1 = __builtin_elementwise_fma(q1y, ay, s1);
    s1 = __builtin_elementwise_fma(q1z, az, s1);
    s1 = __builtin_elementwise_fma(q1w, aw, s1);
    s1 = __builtin_elementwise_fma(q1u, au, s1);
    s1 = __builtin_elementwise_fma(q1v, av, s1);
    s1 = __builtin_elementwise_fma(mh, Xa, s1);
    int jb = j0 + 2 * pr;
    float sA0 = s0.x, sA1 = s0.y, sB0 = s1.x, sB1 = s1.y;
    if (SELF) {
      if (jb + 0 == q0) sA0 = -INFINITY;
      if (jb + 1 == q0) sA1 = -INFINITY;
      if (jb + 0 == q1) sB0 = -INFINITY;
      if (jb + 1 == q1) sB1 = -INFINITY;
    }
    ins3m(sA0, jb + 0, a0, a1, a2, ia0, ia1, ia2);
    ins3m(sA1, jb + 1, a0, a1, a2, ia0, ia1, ia2);
    ins3m(sB0, jb + 0, b0, b1, b2, ib0, ib1, ib2);
    ins3m(sB1, jb + 1, b0, b1, b2, ib0, ib1, ib2);
  }
}

// ---------------------------------------------------------------------------
// Kernel 1: full KNN per block. Block = 1024 thr = 16 waves, 128 queries
// (2 per lane: q0=lane, q1=lane+64), 16 segments of 128 points. Grid = 256.
// Per-pair loads serve 2 queries (r8-r11 showed knn time == load-pipe time:
// halving loads/score is the lever). 3+3 bitonic LDS merge tree -> knn4.
// ---------------------------------------------------------------------------
__global__ __launch_bounds__(1024) void knn_kernel(
    const float4* __restrict__ pts, const float4* __restrict__ ptsP,
    int4* __restrict__ knn4) {
  __shared__ float lv0[16][128], lv1[16][128], lv2[16][128];   // 24 KB
  __shared__ int   li0[16][128], li1[16][128], li2[16][128];   // 24 KB
  int lane = threadIdx.x & 63;
  int w = threadIdx.x >> 6;                 // segment 0..15
  int bk = blockIdx.x >> 4, qg = blockIdx.x & 15;
  int base = bk * NPT;
  int q0 = qg * 128 + lane;
  int q1 = q0 + 64;
  float4 qa0 = pts[(size_t)(base + q0) * 2 + 0];
  float4 qb0 = pts[(size_t)(base + q0) * 2 + 1];
  float4 qa1 = pts[(size_t)(base + q1) * 2 + 0];
  float4 qb1 = pts[(size_t)(base + q1) * 2 + 1];
  int j0 = __builtin_amdgcn_readfirstlane(w * 128);
  const float4* pp4 = ptsP + ((size_t)(base + j0) >> 1) * 4;
  float a0 = -INFINITY, a1 = -INFINITY, a2 = -INFINITY;
  int   ia0 = 0x7fffffff, ia1 = 0x7fffffff, ia2 = 0x7fffffff;
  float b0 = -INFINITY, b1 = -INFINITY, b2 = -INFINITY;
  int   ib0 = 0x7fffffff, ib1 = 0x7fffffff, ib2 = 0x7fffffff;
  if (w == qg) scan128Q2<true >(pp4, j0, q0, q1, qa0, qb0, qa1, qb1,
                                a0, a1, a2, ia0, ia1, ia2, b0, b1, b2, ib0, ib1, ib2);
  else         scan128Q2<false>(pp4, j0, q0, q1, qa0, qb0, qa1, qb1,
                                a0, a1, a2, ia0, ia1, ia2, b0, b1, b2, ib0, ib1, ib2);
  lv0[w][lane] = a0; lv1[w][lane] = a1; lv2[w][lane] = a2;
  li0[w][lane] = ia0; li1[w][lane] = ia1; li2[w][lane] = ia2;
  lv0[w][lane + 64] = b0; lv1[w][lane + 64] = b1; lv2[w][lane + 64] = b2;
  li0[w][lane + 64] = ib0; li1[w][lane + 64] = ib1; li2[w][lane + 64] = ib2;
  __syncthreads();
#pragma unroll
  for (int str = 8; str >= 1; str >>= 1) {
    if (w < str) {
#pragma unroll
      for (int h = 0; h < 2; ++h) {
        int qi = lane + 64 * h;
        float x0 = lv0[w][qi], x1 = lv1[w][qi], x2 = lv2[w][qi];
        int   j0_ = li0[w][qi], j1_ = li1[w][qi], j2_ = li2[w][qi];
        float y0 = lv0[w + str][qi], y1 = lv1[w + str][qi], y2 = lv2[w + str][qi];
        int   k0_ = li0[w + str][qi], k1_ = li1[w + str][qi], k2_ = li2[w + str][qi];
        // bitonic 3+3 -> top-3 (half-cleaner + sort3), total order (desc, idx asc)
        ce(x0, j0_, y2, k2_); ce(x1, j1_, y1, k1_); ce(x2, j2_, y0, k0_);
        ce(x0, j0_, x1, j1_); ce(x1, j1_, x2, j2_); ce(x0, j0_, x1, j1_);
        lv0[w][qi] = x0; lv1[w][qi] = x1; lv2[w][qi] = x2;
        li0[w][qi] = j0_; li1[w][qi] = j1_; li2[w][qi] = j2_;
      }
    }
    __syncthreads();
  }
  if (w == 0) {
    knn4[base + q0] = make_int4(q0, li0[0][lane], li1[0][lane], li2[0][lane]);
    knn4[base + q1] = make_int4(q1, li0[0][lane + 64], li1[0][lane + 64], li2[0][lane + 64]);
  }
}

// ---------------------------------------------------------------------------
// Kernel 2 (round-9 exact)
// ---------------------------------------------------------------------------
__global__ __launch_bounds__(128) void feature_kernel(
    const float4* __restrict__ pts, const int4* __restrict__ knn4,
    const float* __restrict__ W1f, const float* __restrict__ W1d,
    const float4* __restrict__ wpk,
    float4* __restrict__ partials) {
  __shared__ float4 hlds[16][97];          // [p][c*3+j] f4 over kk; x1 overlay at [p][0..31]
  __shared__ float  dlds[16][33];          // [p][o] dot3
  int p = threadIdx.x >> 3;        // 0..15
  int og = threadIdx.x & 7;        // o = og + 8m
  int bk = blockIdx.x >> 7, pb = blockIdx.x & 127;
  int n = (pb << 4) | p;
  int base = bk * NPT;
  float4 ca = pts[(size_t)(base + n) * 2 + 0], cbv = pts[(size_t)(base + n) * 2 + 1];
  float ct[6] = {ca.x, ca.y, ca.z, ca.w, cbv.x, cbv.y};
  float w1f[4][4], w1d[4][4];
#pragma unroll
  for (int m = 0; m < 4; ++m) {
    float4 wf = reinterpret_cast<const float4*>(W1f)[og + 8 * m];
    float4 wd = reinterpret_cast<const float4*>(W1d)[og + 8 * m];
    w1f[m][0] = wf.x; w1f[m][1] = wf.y; w1f[m][2] = wf.z; w1f[m][3] = wf.w;
    w1d[m][0] = wd.x; w1d[m][1] = wd.y; w1d[m][2] = wd.z; w1d[m][3] = wd.w;
  }
  int4 nb = knn4[base + n];
  int nbi[4] = {nb.x, nb.y, nb.z, nb.w};
  float h[4][4][3];                // [m][kk][j]
#pragma unroll
  for (int kk = 0; kk < 4; ++kk) {
    int mi = nbi[kk];
    float4 A = pts[(size_t)(base + mi) * 2 + 0], B = pts[(size_t)(base + mi) * 2 + 1];
    float nc[6] = {A.x, A.y, A.z, A.w, B.x, B.y};
    float G[4][3];
#pragma unroll
    for (int j = 0; j < 3; ++j) {
      G[0][j] = nc[j] - ct[j];
      G[1][j] = nc[3 + j] - ct[3 + j];
      G[2][j] = ct[j];
      G[3][j] = ct[3 + j];
    }
#pragma unroll
    for (int m = 0; m < 4; ++m) {
      float pvv[3], dv[3];
#pragma unroll
      for (int j = 0; j < 3; ++j) {
        float a = 0.f, dd = 0.f;
#pragma unroll
        for (int c = 0; c < 4; ++c) { a = fmaf(w1f[m][c], G[c][j], a); dd = fmaf(w1d[m][c], G[c][j], dd); }
        pvv[j] = a; dv[j] = dd;
      }
      float dot = pvv[0] * dv[0] + pvv[1] * dv[1] + pvv[2] * dv[2];
      float d2  = dv[0] * dv[0] + dv[1] * dv[1] + dv[2] * dv[2];
      float fac = dot / (d2 + EPSF);
#pragma unroll
      for (int j = 0; j < 3; ++j) {
        float negj = pvv[j] - fac * dv[j];
        float sel = (dot >= 0.f) ? pvv[j] : negj;
        h[m][kk][j] = SLOPEF * pvv[j] + (1.f - SLOPEF) * sel;
      }
    }
  }
#pragma unroll
  for (int m = 0; m < 4; ++m)
#pragma unroll
    for (int j = 0; j < 3; ++j)
      hlds[p][(og + 8 * m) * 3 + j] =
          make_float4(h[m][0][j], h[m][1][j], h[m][2][j], h[m][3][j]);
  __syncthreads();
  float4 d1j0[4], d1j1[4], d1j2[4];
#pragma unroll
  for (int m = 0; m < 4; ++m) {
    d1j0[m] = make_float4(0.f, 0.f, 0.f, 0.f);
    d1j1[m] = make_float4(0.f, 0.f, 0.f, 0.f);
    d1j2[m] = make_float4(0.f, 0.f, 0.f, 0.f);
  }
  for (int c = 0; c < 32; ++c) {
    float4 wv = wpk[c * 8 + og];
    float4 h0 = hlds[p][c * 3 + 0];
    float4 h1 = hlds[p][c * 3 + 1];
    float4 h2 = hlds[p][c * 3 + 2];
#pragma unroll
    for (int m = 0; m < 4; ++m) {
      float wm = COMP(wv, m);
      fma4(d1j0[m], wm, h0);
      fma4(d1j1[m], wm, h1);
      fma4(d1j2[m], wm, h2);
    }
  }
  float x1[4][3];
#pragma unroll
  for (int m = 0; m < 4; ++m) {
    float best = -INFINITY;
    float xa = 0.f, xb = 0.f, xc = 0.f;
#pragma unroll
    for (int kk = 0; kk < 4; ++kk) {
      float dt = h[m][kk][0] * COMP(d1j0[m], kk)
               + h[m][kk][1] * COMP(d1j1[m], kk)
               + h[m][kk][2] * COMP(d1j2[m], kk);
      if (dt > best) { best = dt; xa = h[m][kk][0]; xb = h[m][kk][1]; xc = h[m][kk][2]; }
    }
    x1[m][0] = xa; x1[m][1] = xb; x1[m][2] = xc;
  }
  __syncthreads();                  // all reads of h done -> overlay x1
#pragma unroll
  for (int m = 0; m < 4; ++m)
    hlds[p][og + 8 * m] = make_float4(x1[m][0], x1[m][1], x1[m][2], 0.f);
  __syncthreads();
  float d3[4][3] = {};
  for (int c = 0; c < 32; ++c) {
    float4 wv = wpk[256 + c * 8 + og];
    float4 xv = hlds[p][c];
#pragma unroll
    for (int m = 0; m < 4; ++m) {
      float wm = COMP(wv, m);
      d3[m][0] = fmaf(wm, xv.x, d3[m][0]);
      d3[m][1] = fmaf(wm, xv.y, d3[m][1]);
      d3[m][2] = fmaf(wm, xv.z, d3[m][2]);
    }
  }
#pragma unroll
  for (int m = 0; m < 4; ++m)
    dlds[p][og + 8 * m] = x1[m][0] * d3[m][0] + x1[m][1] * d3[m][1] + x1[m][2] * d3[m][2];
  __syncthreads();
  if (threadIdx.x < 32) {
    int o = threadIdx.x;
    float bd = -INFINITY; int wp_ = 0;
#pragma unroll
    for (int p2 = 0; p2 < 16; ++p2) {
      float dv = dlds[p2][o];
      if (dv > bd) { bd = dv; wp_ = p2; }      // strict '>': first n wins
    }
    float4 xv = hlds[wp_][o];
    partials[(((size_t)(bk * 32 + o)) << 7) | pb] = make_float4(xv.x, xv.y, xv.z, bd);
  }
}

// ---------------------------------------------------------------------------
// Kernel 3 (round-9 exact)
// ---------------------------------------------------------------------------
__global__ __launch_bounds__(256) void poolhead_kernel(
    const float4* __restrict__ partials, const float* __restrict__ Wh2,
    const float* __restrict__ gs, float* __restrict__ out) {
  __shared__ float pl[DIM][3];
  int bk = blockIdx.x;
  int o = threadIdx.x >> 3, tg = threadIdx.x & 7;
  const float4* pp = partials + (((size_t)(bk * 32 + o)) << 7);
  float best = -INFINITY; int bp = 0x7fffffff;
  for (int t = 0; t < 16; ++t) {
    int pb = t * 8 + tg;
    float v = pp[pb].w;
    if (v > best) { best = v; bp = pb; }       // strict '>' within residue class
  }
#pragma unroll
  for (int off = 1; off < 8; off <<= 1) {
    float ov = __shfl_xor(best, off, 8);
    int   op = __shfl_xor(bp, off, 8);
    if (ov > best || (ov == best && op < bp)) { best = ov; bp = op; }
  }
  if (tg == 0) {
    float4 xv = pp[bp];
    pl[o][0] = xv.x; pl[o][1] = xv.y; pl[o][2] = xv.z;
  }
  __syncthreads();
  if (threadIdx.x == 0) {
    float M[3][3];
#pragma unroll
    for (int oo = 0; oo < 3; ++oo) {
      float a0 = 0.f, a1 = 0.f, a2 = 0.f;
      for (int c = 0; c < 32; ++c) {
        float w = Wh2[oo * 32 + c];
        a0 = fmaf(w, pl[c][0], a0);
        a1 = fmaf(w, pl[c][1], a1);
        a2 = fmaf(w, pl[c][2], a2);
      }
      M[0][oo] = a0 + GS_EPSF * gs[bk * 9 + 0 * 3 + oo];
      M[1][oo] = a1 + GS_EPSF * gs[bk * 9 + 1 * 3 + oo];
      M[2][oo] = a2 + GS_EPSF * gs[bk * 9 + 2 * 3 + oo];
    }
    float e1[3], e2[3], e3[3], u[3];
    float nn = sqrtf(M[0][0] * M[0][0] + M[1][0] * M[1][0] + M[2][0] * M[2][0]) + EPSF;
#pragma unroll
    for (int r = 0; r < 3; ++r) e1[r] = M[r][0] / nn;
    float d12 = e1[0] * M[0][1] + e1[1] * M[1][1] + e1[2] * M[2][1];
#pragma unroll
    for (int r = 0; r < 3; ++r) u[r] = M[r][1] - d12 * e1[r];
    nn = sqrtf(u[0] * u[0] + u[1] * u[1] + u[2] * u[2]) + EPSF;
#pragma unroll
    for (int r = 0; r < 3; ++r) e2[r] = u[r] / nn;
    float d13 = e1[0] * M[0][2] + e1[1] * M[1][2] + e1[2] * M[2][2];
    float d23 = e2[0] * M[0][2] + e2[1] * M[1][2] + e2[2] * M[2][2];
#pragma unroll
    for (int r = 0; r < 3; ++r) u[r] = M[r][2] - d13 * e1[r] - d23 * e2[r];
    nn = sqrtf(u[0] * u[0] + u[1] * u[1] + u[2] * u[2]) + EPSF;
#pragma unroll
    for (int r = 0; r < 3; ++r) e3[r] = u[r] / nn;
    float det = e1[0] * (e2[1] * e3[2] - e2[2] * e3[1])
              - e1[1] * (e2[0] * e3[2] - e2[2] * e3[0])
              + e1[2] * (e2[0] * e3[1] - e2[1] * e3[0]);
#pragma unroll
    for (int r = 0; r < 3; ++r) {
      out[bk * 9 + r * 3 + 0] = e1[r] * det;
      out[bk * 9 + r * 3 + 1] = e2[r];
      out[bk * 9 + r * 3 + 2] = e3[r];
    }
  }
}

// ---------------------------------------------------------------------------
extern "C" void kernel_launch(void* const* d_in, const int* in_sizes, int n_in,
                              void* d_out, int out_size, void* d_ws, size_t ws_size,
                              hipStream_t stream) {
  (void)in_sizes; (void)n_in; (void)out_size; (void)ws_size;
  const float* node = (const float*)d_in[0];
  const float* W1f = (const float*)d_in[4];
  const float* W1d = (const float*)d_in[5];
  const float* Wp1 = (const float*)d_in[6];
  const float* Wp3 = (const float*)d_in[7];
  const float* Wh2 = (const float*)d_in[8];
  const float* z   = (const float*)d_in[9];
  const float* gs  = (const float*)d_in[10];

  float4* pts      = (float4*)d_ws;                          // 65536 f4 = 1 MB
  int4*   knn4     = (int4*)(pts + (size_t)BKT * NPT * 2);   // 512 KB
  float4* partials = (float4*)(knn4 + (size_t)BKT * NPT);    // 16*32*128 f4 = 1 MB
  float4* wpk      = partials + (size_t)BKT * 32 * 128;      // 512 f4 = 8 KB
  float4* ptsP     = wpk + 512;                              // 16384 pairs * 4 f4 = 1 MB
  float*  out      = (float*)d_out;

  prep_coords    <<<BKT * NPT / 256, 256, 0, stream>>>(node, z, Wp1, Wp3, pts,
                                                       (float*)ptsP, wpk);
  knn_kernel     <<<BKT * 16, 1024, 0, stream>>>(pts, ptsP, knn4);
  feature_kernel <<<BKT * 128, 128, 0, stream>>>(pts, knn4, W1f, W1d, wpk, partials);
  poolhead_kernel<<<BKT, 256, 0, stream>>>(partials, Wh2, gs, out);
}